// Round 3
// baseline (482.045 us; speedup 1.0000x reference)
//
#include <hip/hip_runtime.h>

#define SLOPE 0.2f
__device__ __forceinline__ float lrelu(float v){ return v > 0.0f ? v : SLOPE*v; }

// ConvTranspose1d(k=4,s=2,p=1), 128->128 ch, input L (LDS), output 2L (LDS).
// Thread = (co = tid&127, q = tid>>7): computes output quarter t in
// [q*L/2, (q+1)*L/2) from inputs i in [q*L/4 - 1, q*L/4 + L/4].
// Tap map (x[i] contributes): w.z->t=2i, w.y->t=2i+1, w.x->t=2i+2, w.w->t=2i-1.
template<int L, bool RELU>
__device__ __forceinline__ void tconv_q(const float* __restrict__ W,
                                        const float* __restrict__ bias,
                                        const float* __restrict__ in,
                                        float* __restrict__ out,
                                        int co, int q)
{
  constexpr int TQ = L/2;   // outputs per thread
  constexpr int NI = L/4;   // interior inputs per thread
  const int i0 = q*NI;
  float acc[TQ];
  {
    const float b = bias[co];
    #pragma unroll
    for (int j=0;j<TQ;j++) acc[j]=b;
  }
  const bool hasM1 = (q > 0);   // wave-uniform
  const bool hasE  = (q < 3);
  #pragma unroll 2
  for (int ci=0; ci<128; ci++){
    const float4 w = *(const float4*)(W + ((size_t)ci*128 + co)*4);
    const float* xin = in + ci*L + i0;
    const float xm1 = hasM1 ? xin[-1] : 0.0f;   // i = i0-1 (dropped at i=-1)
    const float xE  = hasE  ? xin[NI] : 0.0f;   // i = i0+NI (dropped at i=L)
    float xv[NI];
    if constexpr (NI==2){ const float2 t=*(const float2*)xin; xv[0]=t.x; xv[1]=t.y; }
    else if constexpr (NI==4){ const float4 t=*(const float4*)xin;
      xv[0]=t.x; xv[1]=t.y; xv[2]=t.z; xv[3]=t.w; }
    else {
      const float4 t0=*(const float4*)xin; const float4 t1=*(const float4*)(xin+4);
      xv[0]=t0.x; xv[1]=t0.y; xv[2]=t0.z; xv[3]=t0.w;
      xv[4]=t1.x; xv[5]=t1.y; xv[6]=t1.z; xv[7]=t1.w;
    }
    acc[0]    += xm1*w.x;      // t = 2(i0-1)+2 = q*TQ
    acc[TQ-1] += xE *w.w;      // t = 2(i0+NI)-1 = q*TQ+TQ-1
    #pragma unroll
    for (int li=0; li<NI; li++){
      const float x = xv[li];
      acc[2*li]   += x*w.z;
      acc[2*li+1] += x*w.y;
      if (li<NI-1) acc[2*li+2] += x*w.x;   // li=NI-1 handled by next q's xm1
      if (li>0)    acc[2*li-1] += x*w.w;   // li=0 handled by prev q's xE
    }
  }
  float* op = out + co*(2*L) + q*TQ;
  #pragma unroll
  for (int j=0;j<TQ;j++) op[j] = RELU ? lrelu(acc[j]) : acc[j];
}

extern "C" __global__ __launch_bounds__(512, 6)
void npg_compute(const float* __restrict__ x,
                 const float* __restrict__ noise,
                 const float* __restrict__ Wup, const float* __restrict__ bup,
                 const float* __restrict__ Wd0, const float* __restrict__ bd0,
                 const float* __restrict__ Wd1, const float* __restrict__ bd1,
                 const float* __restrict__ Wd2, const float* __restrict__ bd2,
                 const float* __restrict__ Wdo, const float* __restrict__ bdo,
                 const float* __restrict__ Wc0, const float* __restrict__ bc0,
                 const float* __restrict__ Wc1, const float* __restrict__ bc1,
                 const float* __restrict__ Wc2, const float* __restrict__ bc2,
                 const float* __restrict__ Wc3, const float* __restrict__ bc3,
                 float* __restrict__ outp)
{
  // LDS pool: ~51 KB -> 3 blocks/CU. Aliasing is phase-safe:
  //   xrow/h0/h1 live only until up-linear completes; bufB first written by tconv1.
  //   fr is first written after bufA's last read (tconv3 input).
  __shared__ float bufB[128*64];   // 32 KB
  __shared__ float bufA[128*32];   // 16 KB
  __shared__ float part[512];      // 2 KB  (live in decay head AND final tconv)
  __shared__ float sdecay;         // read at the very end (scan) - keep separate

  float* const xrow = bufB;        // [0:128)
  float* const h0   = bufB + 128;  // [128:256)
  float* const h1   = bufB + 256;  // [256:384)
  float* const fr   = bufA;        // [0:128)

  const int tid = threadIdx.x;
  const int row = blockIdx.x;
  const int c   = tid & 127;
  const int g   = tid >> 7;

  if (tid < 128) xrow[tid] = x[row*128 + tid];
  __syncthreads();

  // ---- decay head: 3x dense(128x128)+lrelu, 4-way ci split + LDS reduce ----
  {
    const float* inb = xrow;
    const float* Ws[3] = {Wd0, Wd1, Wd2};
    const float* bs[3] = {bd0, bd1, bd2};
    float* outs[3] = {h0, h1, h0};
    #pragma unroll
    for (int layer=0; layer<3; layer++){
      float a = 0.0f;
      const int base = g*32;
      const float* W = Ws[layer];
      #pragma unroll 8
      for (int i=0;i<32;i++) a += inb[base+i]*W[(size_t)(base+i)*128 + c];
      part[g*128 + c] = a;
      __syncthreads();
      if (tid < 128){
        const float v = part[tid]+part[128+tid]+part[256+tid]+part[384+tid] + bs[layer][tid];
        outs[layer][tid] = lrelu(v);
      }
      __syncthreads();
      inb = outs[layer];
    }
    if (tid < 128) part[tid] = h0[tid]*Wdo[tid];
    __syncthreads();
    if (tid < 64){
      float v = part[tid] + part[tid+64];
      #pragma unroll
      for (int off=32; off>0; off>>=1) v += __shfl_down(v, off, 64);
      if (tid==0){
        const float z = v + bdo[0];
        sdecay = 0.8f + 0.2f/(1.0f + expf(-z));
      }
    }
    __syncthreads();
  }

  // ---- up-linear: 1024 outputs, 2 per thread; bufA[o] = xf@Wup + bup ----
  {
    const int o = tid*2;
    float2 a = make_float2(bup[o], bup[o+1]);
    #pragma unroll 4
    for (int i=0;i<128;i++){
      const float xv = xrow[i];
      const float2 w = *(const float2*)(Wup + (size_t)i*1024 + o);
      a.x += xv*w.x; a.y += xv*w.y;
    }
    bufA[o] = a.x; bufA[o+1] = a.y;   // layout [co*8 + s]
    __syncthreads();
  }

  // ---- tconv chain: 8 -> 16 -> 32 -> 64 frames ----
  tconv_q<8 , true>(Wc0, bc0, bufA, bufB, c, g); __syncthreads();
  tconv_q<16, true>(Wc1, bc1, bufB, bufA, c, g); __syncthreads();
  tconv_q<32, true>(Wc2, bc2, bufA, bufB, c, g); __syncthreads();

  // ---- final tconv 128ch -> 1ch (64 -> 128), no lrelu; square; 4-way ci split ----
  {
    const int t = c;
    const bool even = ((t & 1) == 0);
    const int i  = t >> 1;
    const int ia = even ? (i-1) : i;
    const int ib = even ? i : (i+1);
    const float ma = (ia >= 0) ? 1.0f : 0.0f;
    const float mb = (ib < 64) ? 1.0f : 0.0f;
    const int iac = (ia >= 0) ? ia : 0;
    const int ibc = (ib < 64) ? ib : 63;
    float a = 0.0f;
    const int cb = g*32;
    #pragma unroll 4
    for (int k=0;k<32;k++){
      const int ci = cb + k;
      const float4 w = *(const float4*)(Wc3 + (size_t)ci*4);
      const float wa = even ? w.x : w.y;
      const float wb = even ? w.z : w.w;
      a += (bufB[ci*64 + iac]*ma)*wa + (bufB[ci*64 + ibc]*mb)*wb;
    }
    part[g*128 + t] = a;
    __syncthreads();
    if (tid < 128){
      const float s = part[tid]+part[128+tid]+part[256+tid]+part[384+tid] + bc3[0];
      fr[tid] = s*s;     // fr aliases bufA - bufA dead after tconv3
    }
    __syncthreads();
  }

  // ---- weighted inclusive scan: v[t] = sum_{s<=t} decay^(t-s)*u[s] ----
  {
    float d = sdecay;
    #pragma unroll
    for (int o=1;o<128;o<<=1){
      const float prev = (tid < 128 && tid >= o) ? fr[tid-o] : 0.0f;
      __syncthreads();
      if (tid < 128) fr[tid] += d*prev;
      __syncthreads();
      d = d*d;
    }
  }

  // ---- fused interp epilogue: 128 -> 32768 (align_corners=False) * noise ----
  // fr[] (scanned) is live in LDS; stream the row directly. Reads are
  // coalesced float4 (64 lanes x 16B = 1KB/wave); fr reads are broadcast-ish
  // (i0 changes every 256 samples). Overlaps BW-bound streaming with other
  // resident blocks' latency-bound compute.
  {
    const float4* __restrict__ nz4 = (const float4*)(noise + (size_t)row*32768);
    float4*       __restrict__ o4  = (float4*)(outp  + (size_t)row*32768);
    #pragma unroll 8
    for (int it=0; it<16; ++it){
      const int idx = it*512 + tid;
      const float4 nz = nz4[idx];
      const int n = idx*4;
      float r[4];
      #pragma unroll
      for (int j=0;j<4;j++){
        float pos = ((float)(n+j) + 0.5f) * (1.0f/256.0f) - 0.5f;
        pos = fminf(fmaxf(pos, 0.0f), 127.0f);
        const int i0 = (int)pos;
        const int i1 = min(i0+1, 127);
        const float w = pos - (float)i0;
        r[j] = fr[i0]*(1.0f-w) + fr[i1]*w;
      }
      float4 o;
      o.x = r[0]*nz.x; o.y = r[1]*nz.y; o.z = r[2]*nz.z; o.w = r[3]*nz.w;
      o4[idx] = o;
    }
  }
}

extern "C" void kernel_launch(void* const* d_in, const int* in_sizes, int n_in,
                              void* d_out, int out_size, void* d_ws, size_t ws_size,
                              hipStream_t stream)
{
  const float* x    = (const float*)d_in[0];
  const float* noise= (const float*)d_in[1];
  const float* Wup  = (const float*)d_in[2];
  const float* bup  = (const float*)d_in[3];
  const float* Wd0  = (const float*)d_in[4];
  const float* bd0  = (const float*)d_in[5];
  const float* Wd1  = (const float*)d_in[6];
  const float* bd1  = (const float*)d_in[7];
  const float* Wd2  = (const float*)d_in[8];
  const float* bd2  = (const float*)d_in[9];
  const float* Wdo  = (const float*)d_in[10];
  const float* bdo  = (const float*)d_in[11];
  const float* Wc0  = (const float*)d_in[12];
  const float* bc0  = (const float*)d_in[13];
  const float* Wc1  = (const float*)d_in[14];
  const float* bc1  = (const float*)d_in[15];
  const float* Wc2  = (const float*)d_in[16];
  const float* bc2  = (const float*)d_in[17];
  const float* Wc3  = (const float*)d_in[18];
  const float* bc3  = (const float*)d_in[19];
  float* out = (float*)d_out;

  hipLaunchKernelGGL(npg_compute, dim3(1024), dim3(512), 0, stream,
                     x, noise, Wup, bup, Wd0, bd0, Wd1, bd1, Wd2, bd2, Wdo, bdo,
                     Wc0, bc0, Wc1, bc1, Wc2, bc2, Wc3, bc3, out);
}

// Round 6
// 465.065 us; speedup vs baseline: 1.0365x; 1.0365x over previous
//
#include <hip/hip_runtime.h>

#define SLOPE 0.2f
__device__ __forceinline__ float lrelu(float v){ return v > 0.0f ? v : SLOPE*v; }

// Generalized ConvTranspose1d(k=4,s=2,p=1) 128->128ch tile.
// Input: LDS [128][IS] holding logical frames [0,LF). Tile covers input frames
// [base, base+LT) -> output frames [2*base, 2*base+2*LT), written to
// out[co*OS + obase + lt] for local lt in [0, 2*LT).
// Thread (co, q in 0..3): computes local outputs [q*TQ, (q+1)*TQ).
// Tap map (x[i] contributes): w.z->t=2i, w.y->t=2i+1, w.x->t=2i+2, w.w->t=2i-1.
// Edge reads at frames i0-1 / i0+NI come from the FULL input buffer (real data
// at interior tile boundaries); masked only at global edges (0, LF).
template<int LT, int LF, int IS, int OS, bool RELU>
__device__ __forceinline__ void tconv_tile(const float* __restrict__ W,
                                           const float* __restrict__ bias,
                                           const float* __restrict__ in,
                                           int base,
                                           float* __restrict__ out,
                                           int obase,
                                           int co, int q)
{
  constexpr int TQ = LT/2;   // outputs per thread
  constexpr int NI = LT/4;   // interior inputs per thread
  const int i0 = base + q*NI;           // global frame of first interior input
  float acc[TQ];
  {
    const float b = bias[co];
    #pragma unroll
    for (int j=0;j<TQ;j++) acc[j]=b;
  }
  const bool hasM1 = (i0 > 0);          // wave-uniform
  const bool hasE  = (i0 + NI < LF);
  #pragma unroll 2
  for (int ci=0; ci<128; ci++){
    const float4 w = *(const float4*)(W + ((size_t)ci*128 + co)*4);
    const float* xin = in + ci*IS + i0;
    const float xm1 = hasM1 ? xin[-1] : 0.0f;   // frame i0-1
    const float xE  = hasE  ? xin[NI] : 0.0f;   // frame i0+NI
    float xv[NI];
    if constexpr (NI==2){ const float2 t=*(const float2*)xin; xv[0]=t.x; xv[1]=t.y; }
    else { const float4 t=*(const float4*)xin;
      xv[0]=t.x; xv[1]=t.y; xv[2]=t.z; xv[3]=t.w; }
    acc[0]    += xm1*w.x;      // t = 2(i0-1)+2 = first output of this q
    acc[TQ-1] += xE *w.w;      // t = 2(i0+NI)-1 = last output of this q
    #pragma unroll
    for (int li=0; li<NI; li++){
      const float x = xv[li];
      acc[2*li]   += x*w.z;
      acc[2*li+1] += x*w.y;
      if (li<NI-1) acc[2*li+2] += x*w.x;   // li=NI-1 handled by next q's xm1
      if (li>0)    acc[2*li-1] += x*w.w;   // li=0 handled by prev q's xE
    }
  }
  float* op = out + co*OS + obase + q*TQ;
  #pragma unroll
  for (int j=0;j<TQ;j++) op[j] = RELU ? lrelu(acc[j]) : acc[j];
}

// Final tconv (128ch -> 1ch) partial for one 32-frame tile of tconv3 output.
// bufC: [128][33], slot0 = halo (frame 32*tt-1; zeroed for tt=0), slots 1..32 =
// frames 32*tt .. 32*tt+31. Window partition: tt=0 -> t in [0,62],
// tt=1 -> t in [63,127]. Includes the part-reduction barrier.
__device__ __forceinline__ void final_tile(const float* __restrict__ Wc3,
                                           const float* __restrict__ bc3,
                                           const float* __restrict__ bufC,
                                           float* __restrict__ part,
                                           float* __restrict__ fr,
                                           int tt, int c, int g, int tid)
{
  const int off = tt*32;
  const int t = c;
  const bool inwin = (tt==0) ? (t < 63) : (t >= 63);
  const bool even = ((t & 1) == 0);
  const int i  = t >> 1;
  const int ia = even ? (i-1) : i;     // taps: even t: w.x@ia, w.z@ib ; odd: w.y@ia, w.w@ib
  const int ib = even ? i : (i+1);
  const int sa = ia - off + 1;         // in [0,32] whenever inwin (slot0=halo/zero)
  const int sbr = ib - off + 1;
  const float mb = (sbr <= 32) ? 1.0f : 0.0f;   // only t=127 masked (ib=64)
  const int sb = (sbr <= 32) ? sbr : 32;
  float a = 0.0f;
  if (inwin){
    const int cb = g*32;
    #pragma unroll 4
    for (int k=0;k<32;k++){
      const int ci = cb + k;
      const float4 w = *(const float4*)(Wc3 + (size_t)ci*4);
      const float wa = even ? w.x : w.y;
      const float wb = even ? w.z : w.w;
      a += bufC[ci*33 + sa]*wa + (bufC[ci*33 + sb]*mb)*wb;
    }
  }
  part[g*128 + t] = a;
  __syncthreads();
  if (tid < 128 && ((tt==0) ? (tid < 63) : (tid >= 63))){
    const float s = part[tid]+part[128+tid]+part[256+tid]+part[384+tid] + bc3[0];
    fr[tid] = s*s;
  }
}

extern "C" __global__ __launch_bounds__(512, 8)
void npg_compute(const float* __restrict__ x,
                 const float* __restrict__ noise,
                 const float* __restrict__ Wup, const float* __restrict__ bup,
                 const float* __restrict__ Wd0, const float* __restrict__ bd0,
                 const float* __restrict__ Wd1, const float* __restrict__ bd1,
                 const float* __restrict__ Wd2, const float* __restrict__ bd2,
                 const float* __restrict__ Wdo, const float* __restrict__ bdo,
                 const float* __restrict__ Wc0, const float* __restrict__ bc0,
                 const float* __restrict__ Wc1, const float* __restrict__ bc1,
                 const float* __restrict__ Wc2, const float* __restrict__ bc2,
                 const float* __restrict__ Wc3, const float* __restrict__ bc3,
                 float* __restrict__ outp)
{
  // LDS pool ~35 KB -> 4 blocks/CU (32 waves = 100% occupancy cap).
  // tconv3 (32->64) is computed in TWO 16-frame tiles consumed immediately by
  // the final tconv, so the 32 KB full output buffer is never materialized.
  // R0: up-out (stride 8), then tconv1 out [128][32]  (tconv2/3 input)
  // R1: xrow/h0/h1, then tconv0 out [128][16], then bufC [128][33]
  __shared__ float R0[128*32];     // 16 KB
  __shared__ float R1[128*33];     // 16.9 KB
  __shared__ float part[512];      // 2 KB
  __shared__ float fr[128];        // 0.5 KB
  __shared__ float sdecay;

  float* const xrow = R1;          // [0:128)
  float* const h0   = R1 + 128;    // [128:256)
  float* const h1   = R1 + 256;    // [256:384)

  const int tid = threadIdx.x;
  const int row = blockIdx.x;
  const int c   = tid & 127;
  const int g   = tid >> 7;

  if (tid < 128) xrow[tid] = x[row*128 + tid];
  __syncthreads();

  // ---- decay head: 3x dense(128x128)+lrelu, 4-way ci split + LDS reduce ----
  {
    const float* inb = xrow;
    const float* Ws[3] = {Wd0, Wd1, Wd2};
    const float* bs[3] = {bd0, bd1, bd2};
    float* outs[3] = {h0, h1, h0};
    #pragma unroll
    for (int layer=0; layer<3; layer++){
      float a = 0.0f;
      const int base = g*32;
      const float* W = Ws[layer];
      #pragma unroll 8
      for (int i=0;i<32;i++) a += inb[base+i]*W[(size_t)(base+i)*128 + c];
      part[g*128 + c] = a;
      __syncthreads();
      if (tid < 128){
        const float v = part[tid]+part[128+tid]+part[256+tid]+part[384+tid] + bs[layer][tid];
        outs[layer][tid] = lrelu(v);
      }
      __syncthreads();
      inb = outs[layer];
    }
    if (tid < 128) part[tid] = h0[tid]*Wdo[tid];
    __syncthreads();
    if (tid < 64){
      float v = part[tid] + part[tid+64];
      #pragma unroll
      for (int off=32; off>0; off>>=1) v += __shfl_down(v, off, 64);
      if (tid==0){
        const float z = v + bdo[0];
        sdecay = 0.8f + 0.2f/(1.0f + expf(-z));
      }
    }
    __syncthreads();
  }

  // ---- up-linear: 1024 outputs, 2 per thread; R0[o] = xf@Wup + bup ----
  {
    const int o = tid*2;
    float2 a = make_float2(bup[o], bup[o+1]);
    #pragma unroll 4
    for (int i=0;i<128;i++){
      const float xv = xrow[i];
      const float2 w = *(const float2*)(Wup + (size_t)i*1024 + o);
      a.x += xv*w.x; a.y += xv*w.y;
    }
    R0[o] = a.x; R0[o+1] = a.y;   // layout [co*8 + s]
    __syncthreads();
  }

  // ---- tconv chain: 8 -> 16 -> 32 frames ----
  tconv_tile<8 , 8, 8, 16, true>(Wc0, bc0, R0, 0, R1, 0, c, g);  __syncthreads();
  tconv_tile<16,16,16, 32, true>(Wc1, bc1, R1, 0, R0, 0, c, g);  __syncthreads();

  // ---- tconv3 (32->64) tile 0: frames 0..31 -> bufC slots 1..32 ----
  tconv_tile<16,32,32, 33, true>(Wc2, bc2, R0, 0, R1, 1, c, g);
  if (tid < 128) R1[tid*33] = 0.0f;           // tile0 halo (frame -1) = 0
  __syncthreads();

  final_tile(Wc3, bc3, R1, part, fr, 0, c, g, tid);   // fr[0..62]
  // halo copy for tile1 (frame 31 -> slot 0); disjoint threads, disjoint addrs
  if (tid >= 128 && tid < 256){
    const int ci = tid - 128;
    R1[ci*33] = R1[ci*33 + 32];
  }
  __syncthreads();

  // ---- tconv3 tile 1: frames 32..63 -> bufC slots 1..32 ----
  tconv_tile<16,32,32, 33, true>(Wc2, bc2, R0, 16, R1, 1, c, g);
  __syncthreads();

  final_tile(Wc3, bc3, R1, part, fr, 1, c, g, tid);   // fr[63..127]
  __syncthreads();

  // ---- weighted inclusive scan: v[t] = sum_{s<=t} decay^(t-s)*u[s] ----
  {
    float d = sdecay;
    #pragma unroll
    for (int o=1;o<128;o<<=1){
      const float prev = (tid < 128 && tid >= o) ? fr[tid-o] : 0.0f;
      __syncthreads();
      if (tid < 128) fr[tid] += d*prev;
      __syncthreads();
      d = d*d;
    }
  }

  // ---- fused interp epilogue: 128 -> 32768 (align_corners=False) * noise ----
  {
    const float4* __restrict__ nz4 = (const float4*)(noise + (size_t)row*32768);
    float4*       __restrict__ o4  = (float4*)(outp  + (size_t)row*32768);
    #pragma unroll 8
    for (int it=0; it<16; ++it){
      const int idx = it*512 + tid;
      const float4 nz = nz4[idx];
      const int n = idx*4;
      float r[4];
      #pragma unroll
      for (int j=0;j<4;j++){
        float pos = ((float)(n+j) + 0.5f) * (1.0f/256.0f) - 0.5f;
        pos = fminf(fmaxf(pos, 0.0f), 127.0f);
        const int i0 = (int)pos;
        const int i1 = min(i0+1, 127);
        const float w = pos - (float)i0;
        r[j] = fr[i0]*(1.0f-w) + fr[i1]*w;
      }
      float4 o;
      o.x = r[0]*nz.x; o.y = r[1]*nz.y; o.z = r[2]*nz.z; o.w = r[3]*nz.w;
      o4[idx] = o;
    }
  }
}

extern "C" void kernel_launch(void* const* d_in, const int* in_sizes, int n_in,
                              void* d_out, int out_size, void* d_ws, size_t ws_size,
                              hipStream_t stream)
{
  const float* x    = (const float*)d_in[0];
  const float* noise= (const float*)d_in[1];
  const float* Wup  = (const float*)d_in[2];
  const float* bup  = (const float*)d_in[3];
  const float* Wd0  = (const float*)d_in[4];
  const float* bd0  = (const float*)d_in[5];
  const float* Wd1  = (const float*)d_in[6];
  const float* bd1  = (const float*)d_in[7];
  const float* Wd2  = (const float*)d_in[8];
  const float* bd2  = (const float*)d_in[9];
  const float* Wdo  = (const float*)d_in[10];
  const float* bdo  = (const float*)d_in[11];
  const float* Wc0  = (const float*)d_in[12];
  const float* bc0  = (const float*)d_in[13];
  const float* Wc1  = (const float*)d_in[14];
  const float* bc1  = (const float*)d_in[15];
  const float* Wc2  = (const float*)d_in[16];
  const float* bc2  = (const float*)d_in[17];
  const float* Wc3  = (const float*)d_in[18];
  const float* bc3  = (const float*)d_in[19];
  float* out = (float*)d_out;

  hipLaunchKernelGGL(npg_compute, dim3(1024), dim3(512), 0, stream,
                     x, noise, Wup, bup, Wd0, bd0, Wd1, bd1, Wd2, bd2, Wdo, bdo,
                     Wc0, bc0, Wc1, bc1, Wc2, bc2, Wc3, bc3, out);
}

// Round 7
// 452.490 us; speedup vs baseline: 1.0653x; 1.0278x over previous
//
#include <hip/hip_runtime.h>

#define SLOPE 0.2f
__device__ __forceinline__ float lrelu(float v){ return v > 0.0f ? v : SLOPE*v; }

// TWO-ROW ConvTranspose1d(k=4,s=2,p=1) 128->128ch tile.
// Input LDS layout: in[ci*(2*IS) + r*IS + frame], frames [0,LF) per row r=0,1.
// Output: out[co*(2*OS) + r*OS + obase + lt], lt in [0,2*LT).
// Tile covers input frames [base, base+LT). Thread (co,q): lt in [q*LT/2,(q+1)*LT/2).
// Tap map (x[i] contributes): w.z->t=2i, w.y->t=2i+1, w.x->t=2i+2, w.w->t=2i-1.
// Each weight float4 is loaded ONCE and applied to BOTH rows (2x FMA per fetch).
template<int LT, int LF, int IS, int OS, bool RELU>
__device__ __forceinline__ void tconv2r(const float* __restrict__ W,
                                        const float* __restrict__ bias,
                                        const float* __restrict__ in, int base,
                                        float* __restrict__ out, int obase,
                                        int co, int q)
{
  constexpr int TQ = LT/2;
  constexpr int NI = LT/4;
  const int i0 = base + q*NI;
  float a0[TQ], a1[TQ];
  {
    const float b = bias[co];
    #pragma unroll
    for (int j=0;j<TQ;j++){ a0[j]=b; a1[j]=b; }
  }
  const bool hasM1 = (i0 > 0);          // wave-uniform
  const bool hasE  = (i0 + NI < LF);
  #pragma unroll 2
  for (int ci=0; ci<128; ci++){
    const float4 w = *(const float4*)(W + ((size_t)ci*128 + co)*4);
    const float* x0 = in + ci*(2*IS) + i0;
    const float* x1 = x0 + IS;
    const float xm10 = hasM1 ? x0[-1] : 0.0f;
    const float xm11 = hasM1 ? x1[-1] : 0.0f;
    const float xE0  = hasE  ? x0[NI] : 0.0f;
    const float xE1  = hasE  ? x1[NI] : 0.0f;
    float v0[NI], v1[NI];
    if constexpr (NI==2){
      const float2 t0=*(const float2*)x0; v0[0]=t0.x; v0[1]=t0.y;
      const float2 t1=*(const float2*)x1; v1[0]=t1.x; v1[1]=t1.y;
    } else {
      const float4 t0=*(const float4*)x0; v0[0]=t0.x; v0[1]=t0.y; v0[2]=t0.z; v0[3]=t0.w;
      const float4 t1=*(const float4*)x1; v1[0]=t1.x; v1[1]=t1.y; v1[2]=t1.z; v1[3]=t1.w;
    }
    a0[0]    += xm10*w.x;   a1[0]    += xm11*w.x;
    a0[TQ-1] += xE0 *w.w;   a1[TQ-1] += xE1 *w.w;
    #pragma unroll
    for (int li=0; li<NI; li++){
      a0[2*li]   += v0[li]*w.z;   a1[2*li]   += v1[li]*w.z;
      a0[2*li+1] += v0[li]*w.y;   a1[2*li+1] += v1[li]*w.y;
      if (li<NI-1){ a0[2*li+2] += v0[li]*w.x; a1[2*li+2] += v1[li]*w.x; }
      if (li>0)   { a0[2*li-1] += v0[li]*w.w; a1[2*li-1] += v1[li]*w.w; }
    }
  }
  float* op0 = out + co*(2*OS) + obase + q*TQ;
  float* op1 = op0 + OS;
  #pragma unroll
  for (int j=0;j<TQ;j++){
    op0[j] = RELU ? lrelu(a0[j]) : a0[j];
    op1[j] = RELU ? lrelu(a1[j]) : a1[j];
  }
}

// Final tconv (128ch -> 1ch) partial, both rows, one 32-frame tile.
// bufC: [128][2][33] (slot0 = halo; frames 32*tt..32*tt+31 in slots 1..32).
// part: [2][512]; fr: [2][128]. Window: tt=0 -> t<63, tt=1 -> t>=63.
__device__ __forceinline__ void final2r(const float* __restrict__ Wc3,
                                        const float* __restrict__ bc3,
                                        const float* __restrict__ bufC,
                                        float* __restrict__ part,
                                        float* __restrict__ fr,
                                        int tt, int c, int g, int tid)
{
  const int off = tt*32;
  const int t = c;
  const bool inwin = (tt==0) ? (t < 63) : (t >= 63);
  const bool even = ((t & 1) == 0);
  const int i  = t >> 1;
  const int ia = even ? (i-1) : i;
  const int ib = even ? i : (i+1);
  const int sa = ia - off + 1;          // in [0,32] whenever inwin
  const int sbr = ib - off + 1;
  const float mb = (sbr <= 32) ? 1.0f : 0.0f;   // only t=127 masked
  const int sb = (sbr <= 32) ? sbr : 32;
  float A0 = 0.0f, A1 = 0.0f;
  if (inwin){
    const int cb = g*32;
    #pragma unroll 4
    for (int k=0;k<32;k++){
      const int ci = cb + k;
      const float4 w = *(const float4*)(Wc3 + (size_t)ci*4);
      const float wa = even ? w.x : w.y;
      const float wb = even ? w.z : w.w;
      const float* bc = bufC + ci*66;
      A0 += bc[sa]*wa + (bc[sb]*mb)*wb;
      A1 += bc[33+sa]*wa + (bc[33+sb]*mb)*wb;
    }
  }
  part[g*128 + t] = A0;
  part[512 + g*128 + t] = A1;
  __syncthreads();
  if (tid < 256){
    const int r = tid >> 7, t2 = tid & 127;
    const bool w2 = (tt==0) ? (t2 < 63) : (t2 >= 63);
    if (w2){
      const float* p = part + r*512;
      const float s = p[t2]+p[128+t2]+p[256+t2]+p[384+t2] + bc3[0];
      fr[r*128 + t2] = s*s;
    }
  }
}

extern "C" __global__ __launch_bounds__(512, 4)
void npg_compute(const float* __restrict__ x,
                 const float* __restrict__ noise,
                 const float* __restrict__ Wup, const float* __restrict__ bup,
                 const float* __restrict__ Wd0, const float* __restrict__ bd0,
                 const float* __restrict__ Wd1, const float* __restrict__ bd1,
                 const float* __restrict__ Wd2, const float* __restrict__ bd2,
                 const float* __restrict__ Wdo, const float* __restrict__ bdo,
                 const float* __restrict__ Wc0, const float* __restrict__ bc0,
                 const float* __restrict__ Wc1, const float* __restrict__ bc1,
                 const float* __restrict__ Wc2, const float* __restrict__ bc2,
                 const float* __restrict__ Wc3, const float* __restrict__ bc3,
                 float* __restrict__ outp)
{
  // 2 rows per block: every weight fetch feeds 2x FMAs; L2 weight traffic halves.
  // LDS ~70 KB -> 2 blocks/CU; grid 512 = exactly 2/CU -> all blocks co-resident.
  // R0: up-out [ci][2][8]; tconv1-out [ci][2][32]
  // R1: xrow[2]/h0[2]/h1[2] (first 768 floats); tconv0-out [ci][2][16]; bufC [ci][2][33]
  __shared__ float R0[128*64];     // 32 KB
  __shared__ float R1[128*66];     // 33 KB
  __shared__ float part[1024];     // 4 KB
  __shared__ float fr[256];        // 1 KB
  __shared__ float sdecay[2];

  const int tid = threadIdx.x;
  const int row0 = blockIdx.x * 2;
  const int c   = tid & 127;
  const int g   = tid >> 7;

  if (tid < 256){
    const int r = tid >> 7;
    R1[tid] = x[(size_t)(row0 + r)*128 + (tid & 127)];   // xrow_r at R1[r*128]
  }
  __syncthreads();

  // ---- decay head, both rows: g = r*2 + gg (gg = ci-half), LDS reduce ----
  {
    const float* Ws[3] = {Wd0, Wd1, Wd2};
    const float* bs[3] = {bd0, bd1, bd2};
    const int inoff[4] = {0, 256, 512, 256};   // + r*128 (xrow, h0, h1, h0)
    const int r  = g >> 1;
    const int gg = g & 1;
    #pragma unroll
    for (int layer=0; layer<3; layer++){
      const float* inb = R1 + inoff[layer] + r*128;
      float a = 0.0f;
      const int base = gg*64;
      const float* W = Ws[layer];
      #pragma unroll 8
      for (int i=0;i<64;i++) a += inb[base+i]*W[(size_t)(base+i)*128 + c];
      part[g*128 + c] = a;                     // = part[r*256 + gg*128 + c]
      __syncthreads();
      if (tid < 256){
        const int rr = tid >> 7, t = tid & 127;
        const float v = part[rr*256 + t] + part[rr*256 + 128 + t] + bs[layer][t];
        R1[inoff[layer+1] + rr*128 + t] = lrelu(v);
      }
      __syncthreads();
    }
    if (tid < 256){
      const int rr = tid >> 7, t = tid & 127;
      part[tid] = R1[256 + rr*128 + t] * Wdo[t];       // h0_r * Wdo
    }
    __syncthreads();
    if (tid < 128){
      const int rr = tid >> 6;                 // wave0 -> row0, wave1 -> row1
      const int lane = tid & 63;
      float v = part[rr*128 + lane] + part[rr*128 + lane + 64];
      #pragma unroll
      for (int off=32; off>0; off>>=1) v += __shfl_down(v, off, 64);
      if (lane == 0){
        const float z = v + bdo[0];
        sdecay[rr] = 0.8f + 0.2f/(1.0f + expf(-z));
      }
    }
    __syncthreads();
  }

  // ---- up-linear: 1024 outputs/row, 2 per thread per row; weight loaded once ----
  {
    const int o = tid*2;
    const int co = o >> 3, s = o & 7;          // s in {0,2,4,6}: o,o+1 same co
    float2 A0 = make_float2(bup[o], bup[o+1]);
    float2 A1 = A0;
    const float* x0 = R1;                      // row0 xrow
    const float* x1 = R1 + 128;                // row1 xrow
    #pragma unroll 4
    for (int i=0;i<128;i++){
      const float2 w = *(const float2*)(Wup + (size_t)i*1024 + o);
      const float xv0 = x0[i], xv1 = x1[i];
      A0.x += xv0*w.x; A0.y += xv0*w.y;
      A1.x += xv1*w.x; A1.y += xv1*w.y;
    }
    float* d0 = R0 + co*16 + s;                // [ci][2][8]
    d0[0] = A0.x; d0[1] = A0.y;
    d0[8] = A1.x; d0[9] = A1.y;
    __syncthreads();
  }

  // ---- tconv chain: 8 -> 16 -> 32 frames (both rows per call) ----
  tconv2r<8 , 8, 8, 16, true>(Wc0, bc0, R0, 0, R1, 0, c, g);  __syncthreads();
  tconv2r<16,16,16, 32, true>(Wc1, bc1, R1, 0, R0, 0, c, g);  __syncthreads();

  // ---- tconv3 (32->64) tile 0: frames 0..31 -> bufC slots 1..32, both rows ----
  tconv2r<16,32,32, 33, true>(Wc2, bc2, R0, 0, R1, 1, c, g);
  if (tid < 256){ const int r = tid>>7, ci = tid&127; R1[ci*66 + r*33] = 0.0f; }
  __syncthreads();

  final2r(Wc3, bc3, R1, part, fr, 0, c, g, tid);   // fr[r][0..62]
  // halo (frame 31 -> slot 0): threads 256..511, after final2r's internal barrier
  if (tid >= 256){
    const int u = tid - 256;
    const int r = u >> 7, ci = u & 127;
    R1[ci*66 + r*33] = R1[ci*66 + r*33 + 32];
  }
  __syncthreads();

  // ---- tconv3 tile 1: frames 32..63 -> bufC slots 1..32 ----
  tconv2r<16,32,32, 33, true>(Wc2, bc2, R0, 16, R1, 1, c, g);
  __syncthreads();

  final2r(Wc3, bc3, R1, part, fr, 1, c, g, tid);   // fr[r][63..127]
  __syncthreads();

  // ---- weighted inclusive scan, both rows in parallel (256 threads) ----
  {
    float d = (tid < 256) ? sdecay[tid >> 7] : 0.0f;
    #pragma unroll
    for (int o=1;o<128;o<<=1){
      float prev = 0.0f;
      if (tid < 256){
        const int r = tid >> 7, t = tid & 127;
        prev = (t >= o) ? fr[r*128 + t - o] : 0.0f;
      }
      __syncthreads();
      if (tid < 256){
        const int r = tid >> 7, t = tid & 127;
        fr[r*128 + t] += d*prev;
      }
      __syncthreads();
      d = d*d;
    }
  }

  // ---- fused interp epilogue: 128 -> 32768 * noise, both rows ----
  {
    #pragma unroll
    for (int r=0;r<2;r++){
      const float* frr = fr + r*128;
      const float4* __restrict__ nz4 = (const float4*)(noise + (size_t)(row0+r)*32768);
      float4*       __restrict__ o4  = (float4*)(outp  + (size_t)(row0+r)*32768);
      #pragma unroll 4
      for (int it=0; it<16; ++it){
        const int idx = it*512 + tid;
        const float4 nz = nz4[idx];
        const int n = idx*4;
        float rv[4];
        #pragma unroll
        for (int j=0;j<4;j++){
          float pos = ((float)(n+j) + 0.5f) * (1.0f/256.0f) - 0.5f;
          pos = fminf(fmaxf(pos, 0.0f), 127.0f);
          const int i0 = (int)pos;
          const int i1 = min(i0+1, 127);
          const float w = pos - (float)i0;
          rv[j] = frr[i0]*(1.0f-w) + frr[i1]*w;
        }
        float4 o;
        o.x = rv[0]*nz.x; o.y = rv[1]*nz.y; o.z = rv[2]*nz.z; o.w = rv[3]*nz.w;
        o4[idx] = o;
      }
    }
  }
}

extern "C" void kernel_launch(void* const* d_in, const int* in_sizes, int n_in,
                              void* d_out, int out_size, void* d_ws, size_t ws_size,
                              hipStream_t stream)
{
  const float* x    = (const float*)d_in[0];
  const float* noise= (const float*)d_in[1];
  const float* Wup  = (const float*)d_in[2];
  const float* bup  = (const float*)d_in[3];
  const float* Wd0  = (const float*)d_in[4];
  const float* bd0  = (const float*)d_in[5];
  const float* Wd1  = (const float*)d_in[6];
  const float* bd1  = (const float*)d_in[7];
  const float* Wd2  = (const float*)d_in[8];
  const float* bd2  = (const float*)d_in[9];
  const float* Wdo  = (const float*)d_in[10];
  const float* bdo  = (const float*)d_in[11];
  const float* Wc0  = (const float*)d_in[12];
  const float* bc0  = (const float*)d_in[13];
  const float* Wc1  = (const float*)d_in[14];
  const float* bc1  = (const float*)d_in[15];
  const float* Wc2  = (const float*)d_in[16];
  const float* bc2  = (const float*)d_in[17];
  const float* Wc3  = (const float*)d_in[18];
  const float* bc3  = (const float*)d_in[19];
  float* out = (float*)d_out;

  hipLaunchKernelGGL(npg_compute, dim3(512), dim3(512), 0, stream,
                     x, noise, Wup, bup, Wd0, bd0, Wd1, bd1, Wd2, bd2, Wdo, bdo,
                     Wc0, bc0, Wc1, bc1, Wc2, bc2, Wc3, bc3, out);
}